// Round 1
// 1306.325 us; speedup vs baseline: 1.4362x; 1.4362x over previous
//
#include <hip/hip_runtime.h>
#include <math.h>

#define MSZ   1048576ull  // 1024*1024 elements per matrix slot
#define NMAT  33          // matrix 0 = L0, matrices 1..32 = per-batch L
#define PANSZ 61440       // 960*64 shorts per matrix per panel plane
#define NSINK 14

__device__ __forceinline__ float frcp(float x){ return __builtin_amdgcn_rcpf(x); }

typedef __attribute__((ext_vector_type(8)))  short  bfrag;   // 8 x bf16 (4 VGPR)
typedef __attribute__((ext_vector_type(8)))  unsigned short u16x8;
typedef __attribute__((ext_vector_type(16))) float  f32x16;  // 32x32 acc

__device__ __forceinline__ unsigned short bf16rn(float x){
  unsigned u = __float_as_uint(x);
  unsigned r = u + 0x7fffu + ((u>>16)&1u);
  return (unsigned short)(r>>16);
}
__device__ __forceinline__ float bf2f(unsigned short h){
  return __uint_as_float(((unsigned)h)<<16);
}

// ---------------------------------------------------------------- setup
// blocks 0..3: V = softmax(Vc)    blocks 4..4099: Ws = symmetrized sigmoid(W)
__global__ void k_misc(const float* __restrict__ Vc, float* __restrict__ V,
                       const float* __restrict__ W, float* __restrict__ Ws){
  int t = threadIdx.x;
  if(blockIdx.x < 4){
    int i = blockIdx.x*256 + t;
    float4 v = ((const float4*)Vc)[i];
    float mx = fmaxf(fmaxf(v.x,v.y), fmaxf(v.z,v.w));
    float e0=__expf(v.x-mx), e1=__expf(v.y-mx), e2=__expf(v.z-mx), e3=__expf(v.w-mx);
    float is = 1.f/(e0+e1+e2+e3);
    ((float4*)V)[i] = make_float4(e0*is, e1*is, e2*is, e3*is);
  } else {
    int idx = (blockIdx.x-4)*256 + t;
    int i = idx>>10, j = idx&1023;
    float v = 0.f;
    if(i != j){
      float w = (i>j) ? W[i*1024+j] : W[j*1024+i];
      v = 1.f/(1.f+__expf(-w));
    }
    Ws[idx]=v;
  }
}

__global__ void k_pr_y(const float* __restrict__ V, const int* __restrict__ x,
                       float* __restrict__ PrInv, float* __restrict__ y){
  int b = blockIdx.x, t = threadIdx.x;
  __shared__ float red[256];
  float acc = 0.f;
  for(int i=t; i<1024; i+=256){
    int xv = x[b*1024+i];
    float pr = V[i*4+xv];
    PrInv[b*1024+i] = 1.f/pr;
    acc += logf(pr + 1e-7f);
  }
  red[t]=acc; __syncthreads();
  for(int s=128;s>0;s>>=1){ if(t<s) red[t]+=red[t+s]; __syncthreads(); }
  if(t==0) y[b]=red[0];
}

// ---------------------------------------------------------------- sinkhorn + WP
__global__ void __launch_bounds__(256) k_sinkhorn(
    const float* __restrict__ Ec, const float* __restrict__ V,
    const float* __restrict__ Ws, const float* __restrict__ PrInv,
    const int* __restrict__ x, float* __restrict__ mats,
    float* __restrict__ partial){
  int idx = blockIdx.x*256 + threadIdx.x;
  int i = idx>>10, j = idx&1023;   // block covers fixed i, 256 consecutive j
  if(i==0) return;                 // row 0 of WP never needed (whole blocks)
  int t = threadIdx.x;
  int lane = t & 63, wv = t >> 6;
  __shared__ float sE[256][17];
  float E[16];
  {
    const float4* p = (const float4*)(Ec + (size_t)idx*16);
    float4 q0=p[0], q1=p[1], q2=p[2], q3=p[3];
    E[0]=__expf(q0.x); E[1]=__expf(q0.y); E[2]=__expf(q0.z); E[3]=__expf(q0.w);
    E[4]=__expf(q1.x); E[5]=__expf(q1.y); E[6]=__expf(q1.z); E[7]=__expf(q1.w);
    E[8]=__expf(q2.x); E[9]=__expf(q2.y); E[10]=__expf(q2.z); E[11]=__expf(q2.w);
    E[12]=__expf(q3.x);E[13]=__expf(q3.y);E[14]=__expf(q3.z); E[15]=__expf(q3.w);
  }
  float s0=0.f;
  #pragma unroll
  for(int q=0;q<16;q++) s0+=E[q];
  float is0 = frcp(s0);
  #pragma unroll
  for(int q=0;q<16;q++) E[q]*=is0;
  float av[4], bv[4];
  {
    float4 va = ((const float4*)V)[i];
    av[0]=va.x; av[1]=va.y; av[2]=va.z; av[3]=va.w;
    float4 vb = ((const float4*)V)[j];
    bv[0]=vb.x; bv[1]=vb.y; bv[2]=vb.z; bv[3]=vb.w;
  }
  for(int it=0; it<NSINK; ++it){
    #pragma unroll
    for(int r=0;r<4;r++){
      float rs = E[4*r]+E[4*r+1]+E[4*r+2]+E[4*r+3];
      float sc = av[r]*frcp(rs+1e-7f);
      E[4*r]*=sc; E[4*r+1]*=sc; E[4*r+2]*=sc; E[4*r+3]*=sc;
    }
    #pragma unroll
    for(int c=0;c<4;c++){
      float cs = E[c]+E[4+c]+E[8+c]+E[12+c];
      float sc = bv[c]*frcp(cs+1e-7f);
      E[c]*=sc; E[4+c]*=sc; E[8+c]*=sc; E[12+c]*=sc;
    }
  }
  #pragma unroll
  for(int q=0;q<16;q++) sE[t][q] = fminf(fmaxf(E[q],0.f),1.f);
  float wsij = Ws[idx];                 // 0 on diagonal -> val=0 there
  for(int b=0;b<32;b++){
    int xi = x[b*1024+i];               // uniform per block -> scalar load
    int xj = x[b*1024+j];
    float val = sE[t][(xi<<2)+xj] * wsij * PrInv[b*1024+i] * PrInv[b*1024+j];
    if(j!=0)                            // j==0 exists only in the row sum
      mats[(size_t)(1+b)*MSZ + (size_t)(i-1)*1024 + (j-1)] = 1e-7f - val;
    float r = val;                      // wave-reduce row-sum contribution
    r += __shfl_down(r,32); r += __shfl_down(r,16); r += __shfl_down(r,8);
    r += __shfl_down(r,4);  r += __shfl_down(r,2);  r += __shfl_down(r,1);
    if(lane==0)
      partial[((size_t)b<<14) + ((size_t)(i-1)<<4) + ((blockIdx.x&3)<<2) + wv] = r;
  }
}

// ---------------------------------------------------------------- L0 build
__global__ void k_l0(const float* __restrict__ Ws, float* __restrict__ mats){
  int r = blockIdx.x, t = threadIdx.x;
  float* orow = mats + (size_t)r*1024;
  if(r == 1023){
    float4 o = make_float4(0.f,0.f,0.f,0.f);
    if(t==255) o.w = 1.f;
    ((float4*)orow)[t] = o;
    return;
  }
  const float* wrow = Ws + (size_t)(r+1)*1024;
  float4 v = ((const float4*)wrow)[t];
  __shared__ float red[256];
  red[t] = v.x+v.y+v.z+v.w;             // full 1024-col row sum (Ws diag = 0)
  __syncthreads();
  for(int s=128;s>0;s>>=1){ if(t<s) red[t]+=red[t+s]; __syncthreads(); }
  float rs = red[0];
  float o[4];
  #pragma unroll
  for(int q=0;q<4;q++){
    int c = 4*t+q;
    if(c==r)          o[q] = rs + 1e-7f;
    else if(c < 1023) o[q] = 1e-7f - wrow[c+1];
    else              o[q] = 0.f;
  }
  ((float4*)orow)[t] = make_float4(o[0],o[1],o[2],o[3]);
}

// Patch batch matrices: diagonal = rowsum+1e-7 (from partials), clear padding.
__global__ void k_patch(float* __restrict__ mats, const float* __restrict__ partial){
  int m = blockIdx.y + 1;
  int r = blockIdx.x*256 + threadIdx.x;   // 0..1023
  float* A = mats + (size_t)m*MSZ;
  A[(size_t)r*1024 + 1023] = (r==1023) ? 1.f : 0.f;   // col 1023 (+corner)
  if(r < 1023){
    A[(size_t)1023*1024 + r] = 0.f;                   // row 1023
    const float* pp = partial + (((size_t)(m-1))<<14) + ((size_t)r<<4);
    float s = 0.f;
    #pragma unroll
    for(int q=0;q<16;q++) s += pp[q];
    A[(size_t)r*1024 + r] = s + 1e-7f;
  }
}

// ---------------------------------------------------------------- diag LU + inverses
// One block per matrix (33 blocks, 2 waves).  Wave 0: 64x64 shuffle LU (as
// before) + logdet, LU rows -> LDS (zero-padded L-strict / U-strict + 1/diag).
// Then wave 0 computes Uinv columns, wave 1 computes Linv columns — each lane
// owns one column; inner sums are UNIFORM broadcast float4 LDS reads, so this
// is issue-bound, not latency-bound, and it runs ONCE per matrix instead of
// once per trailing block.  Outputs split-bf16 UinvT (row-major [q][p]) and
// Linv (row-major [r][p]) — exactly the MFMA B-fragment layouts k_trsm needs.
__global__ void __launch_bounds__(128) k_diag(const float* __restrict__ mats_,
    unsigned short* __restrict__ UiH, unsigned short* __restrict__ UiL,
    unsigned short* __restrict__ LiH, unsigned short* __restrict__ LiL,
    float* __restrict__ logdet, int k){
  int m = blockIdx.x;
  const float* A = mats_ + (size_t)m*MSZ;
  int t = threadIdx.x;
  int lane = t & 63, w = t >> 6;
  __shared__ float Us[64*68];   // strict upper (diag excluded), zero elsewhere
  __shared__ float Ls[64*68];   // strict lower, zero elsewhere
  __shared__ float rd[64];      // 1/diag

  if(w==0){
    float row[64];
    const float4* pr = (const float4*)(A + (size_t)(k+lane)*1024 + k);
    #pragma unroll
    for(int q4=0;q4<16;q4++){
      float4 v = pr[q4];
      row[4*q4]=v.x; row[4*q4+1]=v.y; row[4*q4+2]=v.z; row[4*q4+3]=v.w;
    }
    float slog = 0.f;
    #pragma unroll
    for(int c=0;c<64;c++){
      float piv = __shfl(row[c], c);
      slog += logf(fabsf(piv));
      float ip = frcp(piv);
      if(lane==c) rd[c] = ip;
      bool below = lane > c;
      float lic = below ? row[c]*ip : 0.f;
      if(below) row[c] = lic;
      #pragma unroll
      for(int q=c+1;q<64;q++){
        float uq = __shfl(row[q], c);
        row[q] = fmaf(-lic, uq, row[q]);
      }
    }
    #pragma unroll
    for(int q=0;q<64;q++){
      Ls[lane*68+q] = (q<lane) ? row[q] : 0.f;
      Us[lane*68+q] = (q>lane) ? row[q] : 0.f;
    }
    if(lane==0){ if(k==0) logdet[m]=slog; else logdet[m]+=slog; }
  }
  __syncthreads();

  if(w==0){
    // ---- Uinv column `lane` via back substitution (x[r]=0 for r>lane).
    float x[64];
    #pragma unroll
    for(int q=0;q<64;q++) x[q]=0.f;
    float rj = rd[lane];
    #pragma unroll
    for(int r=63;r>=0;r--){
      float a0=0.f,a1=0.f,a2=0.f,a3=0.f;
      #pragma unroll
      for(int c=(r+1)&~3; c<64; c+=4){
        float4 u = *(const float4*)&Us[r*68+c];   // uniform -> broadcast
        a0 = fmaf(u.x, x[c],   a0);
        a1 = fmaf(u.y, x[c+1], a1);
        a2 = fmaf(u.z, x[c+2], a2);
        a3 = fmaf(u.w, x[c+3], a3);
      }
      float s = (a0+a1)+(a2+a3);
      x[r] = (r==lane) ? rj : -s*rd[r];
    }
    // lane holds UinvT row `lane` -> split bf16, contiguous store
    unsigned short* ph = UiH + (size_t)m*4096 + (size_t)lane*64;
    unsigned short* pl = UiL + (size_t)m*4096 + (size_t)lane*64;
    #pragma unroll
    for(int p8=0;p8<8;p8++){
      u16x8 h8, l8;
      #pragma unroll
      for(int e=0;e<8;e++){
        float v = x[p8*8+e];
        unsigned short h = bf16rn(v);
        h8[e]=h; l8[e]=bf16rn(v - bf2f(h));
      }
      ((u16x8*)ph)[p8]=h8; ((u16x8*)pl)[p8]=l8;
    }
  } else {
    // ---- Linv column `lane` via forward substitution (unit diag).
    float x[64];
    #pragma unroll
    for(int q=0;q<64;q++) x[q]=0.f;
    #pragma unroll
    for(int r=0;r<64;r++){
      float a0=0.f,a1=0.f,a2=0.f,a3=0.f;
      #pragma unroll
      for(int c=0; c<((r+3)&~3); c+=4){
        float4 u = *(const float4*)&Ls[r*68+c];   // uniform -> broadcast
        a0 = fmaf(u.x, x[c],   a0);
        a1 = fmaf(u.y, x[c+1], a1);
        a2 = fmaf(u.z, x[c+2], a2);
        a3 = fmaf(u.w, x[c+3], a3);
      }
      x[r] = (r==lane) ? 1.f : -((a0+a1)+(a2+a3));
    }
    // transpose via LDS (Ls no longer needed): Linv row-major
    #pragma unroll
    for(int r=0;r<64;r++) Ls[r*68+lane] = x[r];   // fixed r: lanes consecutive
    unsigned short* ph = LiH + (size_t)m*4096 + (size_t)lane*64;
    unsigned short* pl = LiL + (size_t)m*4096 + (size_t)lane*64;
    #pragma unroll
    for(int p8=0;p8<8;p8++){
      float4 u0 = *(const float4*)&Ls[lane*68 + p8*8];
      float4 u1 = *(const float4*)&Ls[lane*68 + p8*8 + 4];
      float v[8] = {u0.x,u0.y,u0.z,u0.w,u1.x,u1.y,u1.z,u1.w};
      u16x8 h8, l8;
      #pragma unroll
      for(int e=0;e<8;e++){
        unsigned short h = bf16rn(v[e]);
        h8[e]=h; l8[e]=bf16rn(v[e] - bf2f(h));
      }
      ((u16x8*)ph)[p8]=h8; ((u16x8*)pl)[p8]=l8;
    }
  }
}

// ---------------------------------------------------------------- MFMA trsm
// L21 = A21 * Uinv   (blockIdx.x <  nb : 128 trailing rows / block)
// U12^T = A12^T * Linv^T  (blockIdx.x >= nb : 128 trailing cols / block)
// Each wave: 32 rows x 64 out, K=64, 3-term split-bf16 (same numerics as the
// Schur GEMM).  24 MFMAs/wave, no LDS, no barrier: throughput, not latency.
__global__ void __launch_bounds__(256) k_trsm(const float* __restrict__ mats_,
    const unsigned short* __restrict__ UiH, const unsigned short* __restrict__ UiL,
    const unsigned short* __restrict__ LiH, const unsigned short* __restrict__ LiL,
    unsigned short* __restrict__ Ah, unsigned short* __restrict__ Al,
    unsigned short* __restrict__ Bh, unsigned short* __restrict__ Bl,
    int k){
  int m = blockIdx.y;
  const float* A = mats_ + (size_t)m*MSZ;
  int rem = 1024 - (k+64);
  int nb = (rem+127)>>7;
  bool aside = (int)blockIdx.x < nb;
  int t = threadIdx.x, lane = t&63;
  int r32 = lane&31, hi = lane>>5, wv = t>>6;
  int tile0 = (aside ? (int)blockIdx.x : (int)blockIdx.x - nb)*128 + wv*32;
  int rel  = tile0 + r32;
  int relc = min(rel, rem-1);

  const unsigned short* IH = (aside ? UiH : LiH) + (size_t)m*4096;
  const unsigned short* IL = (aside ? UiL : LiL) + (size_t)m*4096;

  // A-operand fragments: 4 kc x 8 elems, split hi/lo in regs
  bfrag ah[4], al[4];
  if(aside){
    const float* src = A + (size_t)(k+64+relc)*1024 + k + hi*8;
    #pragma unroll
    for(int kc=0;kc<4;kc++){
      float4 u0 = *(const float4*)(src + kc*16);
      float4 u1 = *(const float4*)(src + kc*16 + 4);
      float v[8] = {u0.x,u0.y,u0.z,u0.w,u1.x,u1.y,u1.z,u1.w};
      #pragma unroll
      for(int e=0;e<8;e++){
        unsigned short h = bf16rn(v[e]);
        ah[kc][e] = (short)h;
        al[kc][e] = (short)bf16rn(v[e] - bf2f(h));
      }
    }
  } else {
    const float* src = A + (size_t)(k + hi*8)*1024 + (k+64+relc);
    #pragma unroll
    for(int kc=0;kc<4;kc++){
      #pragma unroll
      for(int e=0;e<8;e++){
        float v = src[(size_t)(kc*16+e)*1024];   // fixed row: lanes coalesce
        unsigned short h = bf16rn(v);
        ah[kc][e] = (short)h;
        al[kc][e] = (short)bf16rn(v - bf2f(h));
      }
    }
  }

  f32x16 acc[2];
  #pragma unroll
  for(int ct=0;ct<2;ct++)
    #pragma unroll
    for(int q=0;q<16;q++) acc[ct][q]=0.f;

  #pragma unroll
  for(int kc=0;kc<4;kc++){
    #pragma unroll
    for(int ct=0;ct<2;ct++){
      bfrag bh = *(const bfrag*)(IH + (size_t)(ct*32+r32)*64 + kc*16 + hi*8);
      bfrag bl = *(const bfrag*)(IL + (size_t)(ct*32+r32)*64 + kc*16 + hi*8);
      acc[ct] = __builtin_amdgcn_mfma_f32_32x32x16_bf16(ah[kc], bh, acc[ct], 0,0,0);
      acc[ct] = __builtin_amdgcn_mfma_f32_32x32x16_bf16(ah[kc], bl, acc[ct], 0,0,0);
      acc[ct] = __builtin_amdgcn_mfma_f32_32x32x16_bf16(al[kc], bh, acc[ct], 0,0,0);
    }
  }

  // D layout: lane-dim = out col q (panel k-index), reg-dim = row (A index)
  unsigned short* PH = (aside ? Ah : Bh) + (size_t)m*PANSZ;
  unsigned short* PL = (aside ? Al : Bl) + (size_t)m*PANSZ;
  #pragma unroll
  for(int ct=0;ct<2;ct++){
    #pragma unroll
    for(int reg=0;reg<16;reg++){
      int crow = (reg&3) + ((reg>>2)<<3) + (hi<<2);
      int r = tile0 + crow;
      if(r < rem){
        float v = acc[ct][reg];
        unsigned short h = bf16rn(v);
        size_t off = (size_t)r*64 + ct*32 + r32;
        PH[off] = h;
        PL[off] = bf16rn(v - bf2f(h));
      }
    }
  }
}

// Final 64x64 block (k=960): logdet contribution only.
__global__ void __launch_bounds__(64) k_ld(const float* __restrict__ mats,
                                           float* __restrict__ logdet){
  int m = blockIdx.x, t = threadIdx.x;
  const float* A = mats + (size_t)m*MSZ;
  float row[64];
  #pragma unroll
  for(int q=0;q<64;q++)
    row[q] = A[(size_t)(960+t)*1024 + 960 + q];
  float slog = 0.f;
  #pragma unroll
  for(int c=0;c<64;c++){
    float piv = __shfl(row[c], c);
    slog += logf(fabsf(piv));
    float ip = frcp(piv);
    bool below = t > c;
    float lic = below ? row[c]*ip : 0.f;
    #pragma unroll
    for(int q=c+1;q<64;q++){
      float uq = __shfl(row[q], c);
      row[q] = fmaf(-lic, uq, row[q]);
    }
  }
  if(t==0) logdet[m] += slog;
}

// ------------------------------------------------------- MFMA split-bf16 Schur
// A22 -= L21 * U12.  128x128 C tile, 4 waves, K=64 in two 32-chunks (32 KB LDS
// -> 4 blocks/CU).  Stage-1 global loads issued before stage-0's barrier so
// they overlap stage-0 MFMAs.  Swizzle koct ^ ((row>>1)&3): <=2-way aliasing.
__global__ void __launch_bounds__(256) k_gemm(float* __restrict__ mats,
    const unsigned short* __restrict__ Ah, const unsigned short* __restrict__ Al,
    const unsigned short* __restrict__ Bh, const unsigned short* __restrict__ Bl,
    int k){
  int m = blockIdx.z;
  float* A = mats + (size_t)m*MSZ;
  int rem = 1024 - (k+64);
  int i0rel = blockIdx.y*128;
  int j0rel = blockIdx.x*128;
  __shared__ unsigned short As[2][4096];   // [hi/lo][row*32 + swz(koct)*8]
  __shared__ unsigned short Bs[2][4096];
  int t = threadIdx.x;
  int lane = t & 63, wvi = t >> 6;
  int wr = wvi >> 1, wc = wvi & 1;

  const unsigned short* pAh = Ah + (size_t)m*PANSZ;
  const unsigned short* pAl = Al + (size_t)m*PANSZ;
  const unsigned short* pBh = Bh + (size_t)m*PANSZ;
  const unsigned short* pBl = Bl + (size_t)m*PANSZ;

  int rowA[2], koctA[2], ldsOff[2];
  bool vA[2], vB[2];
  size_t offA[2], offB[2];
  #pragma unroll
  for(int p=0;p<2;p++){
    int c = t + 256*p;
    int row = c>>2, koct = c&3;
    rowA[p]=row; koctA[p]=koct;
    ldsOff[p] = row*32 + ((koct ^ ((row>>1)&3))<<3);
    vA[p] = (i0rel+row) < rem;
    vB[p] = (j0rel+row) < rem;
    offA[p] = (size_t)(i0rel+row)*64 + koct*8;
    offB[p] = (size_t)(j0rel+row)*64 + koct*8;
  }
  u16x8 z; z = 0;

  // stage 0 loads -> LDS
  #pragma unroll
  for(int p=0;p<2;p++){
    u16x8 ah = vA[p] ? *(const u16x8*)(pAh + offA[p]) : z;
    u16x8 al = vA[p] ? *(const u16x8*)(pAl + offA[p]) : z;
    u16x8 bh = vB[p] ? *(const u16x8*)(pBh + offB[p]) : z;
    u16x8 bl = vB[p] ? *(const u16x8*)(pBl + offB[p]) : z;
    *(u16x8*)&As[0][ldsOff[p]] = ah;
    *(u16x8*)&As[1][ldsOff[p]] = al;
    *(u16x8*)&Bs[0][ldsOff[p]] = bh;
    *(u16x8*)&Bs[1][ldsOff[p]] = bl;
  }
  // stage 1 loads issued NOW (land in regs while stage 0 computes)
  u16x8 p1[8];
  #pragma unroll
  for(int p=0;p<2;p++){
    p1[4*p+0] = vA[p] ? *(const u16x8*)(pAh + offA[p] + 32) : z;
    p1[4*p+1] = vA[p] ? *(const u16x8*)(pAl + offA[p] + 32) : z;
    p1[4*p+2] = vB[p] ? *(const u16x8*)(pBh + offB[p] + 32) : z;
    p1[4*p+3] = vB[p] ? *(const u16x8*)(pBl + offB[p] + 32) : z;
  }
  __syncthreads();

  f32x16 acc[2][2];
  #pragma unroll
  for(int rt=0;rt<2;rt++)
    #pragma unroll
    for(int ct=0;ct<2;ct++)
      #pragma unroll
      for(int q=0;q<16;q++) acc[rt][ct][q] = 0.f;

  int kgrp = lane >> 5;
  #pragma unroll
  for(int ks=0; ks<2; ks++){
    #pragma unroll
    for(int kc=0;kc<2;kc++){
      int koct = kc*2 + kgrp;
      bfrag ah[2], al[2], bh[2], bl[2];
      #pragma unroll
      for(int rt=0;rt<2;rt++){
        int row = wr*64 + rt*32 + (lane&31);
        int ad = row*32 + ((koct ^ ((row>>1)&3))<<3);
        ah[rt] = *(const bfrag*)&As[0][ad];
        al[rt] = *(const bfrag*)&As[1][ad];
      }
      #pragma unroll
      for(int ct=0;ct<2;ct++){
        int col = wc*64 + ct*32 + (lane&31);
        int ad = col*32 + ((koct ^ ((col>>1)&3))<<3);
        bh[ct] = *(const bfrag*)&Bs[0][ad];
        bl[ct] = *(const bfrag*)&Bs[1][ad];
      }
      #pragma unroll
      for(int rt=0;rt<2;rt++)
        #pragma unroll
        for(int ct=0;ct<2;ct++){
          acc[rt][ct] = __builtin_amdgcn_mfma_f32_32x32x16_bf16(ah[rt], bh[ct], acc[rt][ct], 0,0,0);
          acc[rt][ct] = __builtin_amdgcn_mfma_f32_32x32x16_bf16(ah[rt], bl[ct], acc[rt][ct], 0,0,0);
          acc[rt][ct] = __builtin_amdgcn_mfma_f32_32x32x16_bf16(al[rt], bh[ct], acc[rt][ct], 0,0,0);
        }
    }
    if(ks==0){
      __syncthreads();   // stage-0 reads done
      #pragma unroll
      for(int p=0;p<2;p++){
        *(u16x8*)&As[0][ldsOff[p]] = p1[4*p+0];
        *(u16x8*)&As[1][ldsOff[p]] = p1[4*p+1];
        *(u16x8*)&Bs[0][ldsOff[p]] = p1[4*p+2];
        *(u16x8*)&Bs[1][ldsOff[p]] = p1[4*p+3];
      }
      __syncthreads();
    }
  }

  // C RMW epilogue (C/D layout: col=lane&31, row=(reg&3)+8*(reg>>2)+4*(lane>>5))
  int r0 = k + 64;
  #pragma unroll
  for(int rt=0;rt<2;rt++){
    int rowblk = i0rel + wr*64 + rt*32;
    if(rowblk >= rem) continue;
    #pragma unroll
    for(int ct=0;ct<2;ct++){
      int colblk = j0rel + wc*64 + ct*32;
      if(colblk >= rem) continue;
      int col = r0 + colblk + (lane&31);
      int rbase = r0 + rowblk + ((lane>>5)<<2);
      #pragma unroll
      for(int reg=0;reg<16;reg++){
        int row = rbase + (reg&3) + ((reg>>2)<<3);
        float* pc = A + (size_t)row*1024 + col;
        *pc -= acc[rt][ct][reg];
      }
    }
  }
}

__global__ void k_final(const float* __restrict__ y, const float* __restrict__ logdet,
                        float* __restrict__ out){
  int b = threadIdx.x;
  if(b<32) out[b] = y[b] + logdet[1+b] - logdet[0];
}

// ---------------------------------------------------------------- launch
extern "C" void kernel_launch(void* const* d_in, const int* in_sizes, int n_in,
                              void* d_out, int out_size, void* d_ws, size_t ws_size,
                              hipStream_t stream){
  (void)in_sizes; (void)n_in; (void)out_size; (void)ws_size;
  const int*   x  = (const int*)d_in[0];
  const float* W  = (const float*)d_in[1];
  const float* Vc = (const float*)d_in[2];
  const float* Ec = (const float*)d_in[3];
  float* out = (float*)d_out;

  char* p = (char*)d_ws;
  auto alloc = [&](size_t bytes)->char*{ char* r = p; p += (bytes+255)&~(size_t)255; return r; };
  float* mats   = (float*)alloc((size_t)NMAT*MSZ*4);           // 138.4 MB
  float* Ws     = (float*)alloc(1048576ull*4);
  unsigned short* Ah = (unsigned short*)alloc((size_t)NMAT*PANSZ*2);
  unsigned short* Al = (unsigned short*)alloc((size_t)NMAT*PANSZ*2);
  unsigned short* Bh = (unsigned short*)alloc((size_t)NMAT*PANSZ*2);
  unsigned short* Bl = (unsigned short*)alloc((size_t)NMAT*PANSZ*2);
  unsigned short* UiH = (unsigned short*)alloc((size_t)NMAT*4096*2);
  unsigned short* UiL = (unsigned short*)alloc((size_t)NMAT*4096*2);
  unsigned short* LiH = (unsigned short*)alloc((size_t)NMAT*4096*2);
  unsigned short* LiL = (unsigned short*)alloc((size_t)NMAT*4096*2);
  float* V      = (float*)alloc(4096*4);
  float* PrInv  = (float*)alloc(32768*4);
  float* partial= (float*)alloc((size_t)32*16384*4);           // 2 MB
  float* y      = (float*)alloc(256);
  float* logdet = (float*)alloc(256);

  k_misc<<<4100,256,0,stream>>>(Vc, V, W, Ws);
  k_pr_y<<<32,256,0,stream>>>(V, x, PrInv, y);
  k_sinkhorn<<<4096,256,0,stream>>>(Ec, V, Ws, PrInv, x, mats, partial);
  k_l0<<<1024,256,0,stream>>>(Ws, mats);
  k_patch<<<dim3(4,32),256,0,stream>>>(mats, partial);

  for(int s=0;s<15;s++){
    int k = 64*s;
    int rem = 1024 - (k+64);
    k_diag<<<NMAT,128,0,stream>>>(mats, UiH,UiL,LiH,LiL, logdet, k);
    int nb = (rem+127)/128;
    k_trsm<<<dim3(2*nb,NMAT),256,0,stream>>>(mats, UiH,UiL,LiH,LiL, Ah,Al,Bh,Bl, k);
    int nt = (rem+127)/128;
    k_gemm<<<dim3(nt,nt,NMAT),256,0,stream>>>(mats, Ah,Al,Bh,Bl, k);
  }
  k_ld<<<NMAT,64,0,stream>>>(mats, logdet);
  k_final<<<1,32,0,stream>>>(y, logdet, out);
}